// Round 5
// baseline (142.503 us; speedup 1.0000x reference)
//
#include <hip/hip_runtime.h>
#include <math.h>

// x is (B=64, C=64, H=64, W=64) fp32, NCHW.
#define BDIM 64
#define CDIM 64
#define HWN  4096            // H*W
#define NROWS (BDIM * HWN)   // 262144 spatial rows
#define CHSTRIDE (CDIM * HWN)
#define EPSV 1e-5f

#define TILE 256                    // hw positions per block
#define ROWBLOCKS (NROWS / TILE)    // 1024 blocks for the per-row passes

// ws layout (floats), no atomics anywhere:
//  [0 .. 4095]          per-(b,c)-plane sums (plane = b*64 + c)   <- K1
//  [4096 .. 5119]       per-block d^2 partials (1024 blocks)      <- K2
//  [8192 .. +NROWS)     alpha per row                             <- K2
//  [COEF .. +NROWS)     coef per row                              <- K2
#define DD_OFF    4096
#define ALPHA_OFF 8192
#define COEF_OFF  (ALPHA_OFF + NROWS)

// ---------------- K1: per-plane sums (contiguous float4) ----------------
__global__ __launch_bounds__(256) void k_chansum(const float* __restrict__ x,
                                                 float* __restrict__ ws) {
    const int plane = blockIdx.x;          // b*C + c
    const float4* p4 = reinterpret_cast<const float4*>(x + (size_t)plane * HWN);
    float s = 0.f;
#pragma unroll
    for (int i = 0; i < HWN / 4 / 256; ++i) {
        float4 v = p4[threadIdx.x + i * 256];
        s += (v.x + v.y) + (v.z + v.w);
    }
    for (int off = 32; off; off >>= 1) s += __shfl_down(s, off, 64);
    __shared__ float red[4];
    const int lane = threadIdx.x & 63, wid = threadIdx.x >> 6;
    if (lane == 0) red[wid] = s;
    __syncthreads();
    if (threadIdx.x == 0) ws[plane] = (red[0] + red[1]) + (red[2] + red[3]);
}

// Per-block redundant mu recompute from plane sums (16 KB of L2-hot reads).
// stmp must hold >=256 floats; smu gets mu[64]. Ends with __syncthreads().
__device__ __forceinline__ void compute_mu(const float* __restrict__ ws,
                                           float* smu, float* stmp) {
    const int t = threadIdx.x, c = t & 63, g = t >> 6;
    float m = 0.f;
#pragma unroll
    for (int b = 0; b < BDIM / 4; ++b) m += ws[(g * (BDIM / 4) + b) * CDIM + c];
    stmp[g * 64 + c] = m;
    __syncthreads();
    if (t < 64) {
        const float msum = (stmp[c] + stmp[64 + c]) + (stmp[128 + c] + stmp[192 + c]);
        const float mval = msum * (1.0f / (float)NROWS);
        float mm = (c == 0) ? mval * mval : -mval * mval;   // m0^2 - sum(m[1:]^2)
        for (int off = 32; off; off >>= 1) mm += __shfl_down(mm, off, 64);
        mm = __shfl(mm, 0, 64);
        smu[c] = mval / sqrtf(fmaxf(mm, EPSV));
    }
    __syncthreads();
}

// Stage a [64][TILE] tile: wave w, step s loads channel c=4s+w as one
// contiguous 1 KB float4 segment. tile layout [c][j], no pad (all accesses
// are row-contiguous). Ends WITHOUT syncthreads.
__device__ __forceinline__ void load_tile(const float* __restrict__ base,
                                          float* __restrict__ tile) {
    const int w = threadIdx.x >> 6, l = threadIdx.x & 63;
#pragma unroll
    for (int s = 0; s < 16; ++s) {
        const int c = s * 4 + w;
        const float4 v = *reinterpret_cast<const float4*>(base + (size_t)c * HWN + 4 * l);
        *reinterpret_cast<float4*>(&tile[c * TILE + 4 * l]) = v;
    }
}

// ---------------- K2: alpha/coef per row + d^2 partials ----------------
__global__ __launch_bounds__(256) void k_alpha(const float* __restrict__ x,
                                               float* __restrict__ ws) {
    __shared__ float tile[CDIM * TILE];    // 64 KB
    __shared__ float smu[64], red[4];
    compute_mu(ws, smu, tile);             // tile doubles as stmp scratch

    const int n0 = blockIdx.x * TILE;
    const int b = n0 >> 12;
    const int hw0 = n0 & (HWN - 1);
    load_tile(x + (size_t)b * CHSTRIDE + hw0, tile);
    __syncthreads();

    const int t = threadIdx.x;             // row j within tile
    // alpha = x0*mu0 - sum_{c>=1} x_c*mu_c ; 4 accumulators to break the chain
    float a0 = tile[t] * smu[0]           - tile[TILE + t] * smu[1];
    float a1 = -tile[2 * TILE + t] * smu[2] - tile[3 * TILE + t] * smu[3];
    float a2 = 0.f, a3 = 0.f;
#pragma unroll
    for (int c = 4; c < CDIM; c += 4) {
        a0 -= tile[(c + 0) * TILE + t] * smu[c + 0];
        a1 -= tile[(c + 1) * TILE + t] * smu[c + 1];
        a2 -= tile[(c + 2) * TILE + t] * smu[c + 2];
        a3 -= tile[(c + 3) * TILE + t] * smu[c + 3];
    }
    float alpha = (a0 + a1) + (a2 + a3);
    alpha = fmaxf(alpha, 1.0f + EPSV);
    const float d = acoshf(alpha);
    const float coef = d / sqrtf(alpha * alpha - 1.0f);
    ws[ALPHA_OFF + n0 + t] = alpha;
    ws[COEF_OFF + n0 + t]  = coef;

    float dd = d * d;
    for (int off = 32; off; off >>= 1) dd += __shfl_down(dd, off, 64);
    const int lane = t & 63, wid = t >> 6;
    if (lane == 0) red[wid] = dd;
    __syncthreads();
    if (t == 0) ws[DD_OFF + blockIdx.x] = (red[0] + red[1]) + (red[2] + red[3]);
}

// ---------------- K3: output transform (tile in, tile out) ----------------
__global__ __launch_bounds__(256) void k_out(const float* __restrict__ x,
                                             const float* __restrict__ gamma,
                                             const float* __restrict__ beta,
                                             float* __restrict__ out,
                                             const float* __restrict__ ws) {
    __shared__ float tile[CDIM * TILE];    // 64 KB
    __shared__ float smu[64], sg[64], sb[64], svar[4];
    compute_mu(ws, smu, tile);             // tile doubles as stmp scratch

    // var: re-reduce the 1024 per-block d^2 partials (L2-hot, 4 KB).
    {
        float pd = ws[DD_OFF + threadIdx.x] + ws[DD_OFF + 256 + threadIdx.x] +
                   ws[DD_OFF + 512 + threadIdx.x] + ws[DD_OFF + 768 + threadIdx.x];
        for (int off = 32; off; off >>= 1) pd += __shfl_down(pd, off, 64);
        const int lane = threadIdx.x & 63, wid = threadIdx.x >> 6;
        if (lane == 0) svar[wid] = pd;
        if (threadIdx.x < 64) {
            sg[threadIdx.x] = (threadIdx.x >= 1) ? gamma[threadIdx.x - 1] : 0.f;
            sb[threadIdx.x] = (threadIdx.x >= 1) ? beta[threadIdx.x - 1] : 0.f;
        }
    }
    __syncthreads();
    const float var = ((svar[0] + svar[1]) + (svar[2] + svar[3])) * (1.0f / (float)NROWS);
    const float inv_sv = 1.0f / (sqrtf(var) + EPSV);

    const int n0 = blockIdx.x * TILE;
    const int b = n0 >> 12;
    const int hw0 = n0 & (HWN - 1);
    const size_t gbase = (size_t)b * CHSTRIDE + hw0;
    load_tile(x + gbase, tile);
    __syncthreads();

    const int t = threadIdx.x;             // row j; column t owned exclusively
    const float al = ws[ALPHA_OFF + n0 + t];
    const float co = ws[COEF_OFF + n0 + t];
    const float m0 = smu[0];
    const float kk = co * (tile[t] - al * m0) / (1.0f + m0);   // v0/(1+mu0)

    float s2 = 0.f;
#pragma unroll
    for (int c = 1; c < CDIM; ++c) {
        const float xv = tile[c * TILE + t];
        const float m = smu[c];
        const float v = co * (xv - al * m);
        const float vo = v - kk * m;             // mu_plus_o[c]==mu[c], c>=1
        const float s = (sg[c] * inv_sv) * vo + sb[c];
        s2 += s * s;
        tile[c * TILE + t] = s;                  // in-place, column-exclusive
    }
    tile[t] = sqrtf(1.0f + s2);                  // t channel (c=0)
    __syncthreads();

    // writeback: wave w, step s writes channel c=4s+w, 1 KB contiguous
    const int w = t >> 6, l = t & 63;
    float* obase = out + gbase;
#pragma unroll
    for (int s = 0; s < 16; ++s) {
        const int c = s * 4 + w;
        const float4 v = *reinterpret_cast<const float4*>(&tile[c * TILE + 4 * l]);
        *reinterpret_cast<float4*>(obase + (size_t)c * HWN + 4 * l) = v;
    }
}

extern "C" void kernel_launch(void* const* d_in, const int* in_sizes, int n_in,
                              void* d_out, int out_size, void* d_ws, size_t ws_size,
                              hipStream_t stream) {
    const float* x     = (const float*)d_in[0];
    const float* gamma = (const float*)d_in[1];
    const float* beta  = (const float*)d_in[2];
    float* out = (float*)d_out;
    float* ws  = (float*)d_ws;

    k_chansum<<<BDIM * CDIM, 256, 0, stream>>>(x, ws);
    k_alpha<<<ROWBLOCKS, 256, 0, stream>>>(x, ws);
    k_out<<<ROWBLOCKS, 256, 0, stream>>>(x, gamma, beta, out, ws);
}